// Round 1
// baseline (2080.451 us; speedup 1.0000x reference)
//
#include <hip/hip_runtime.h>
#include <hip/hip_bf16.h>
#include <cfloat>
#include <math.h>

#define T_TOK 4096
#define H_DIM 2048
#define E_NUM 64
#define I_DIM 1024
#define TOPK  8
#define BM    128
#define BK    64

typedef __attribute__((ext_vector_type(4))) float f32x4;
typedef __attribute__((ext_vector_type(8))) short bf16x8;
typedef __attribute__((ext_vector_type(4))) int   i32x4;

__device__ __forceinline__ unsigned short f2bf(float f) {
    union { float f; unsigned int u; } v; v.f = f;
    unsigned int r = v.u + 0x7FFFu + ((v.u >> 16) & 1u);  // RNE
    return (unsigned short)(r >> 16);
}
__device__ __forceinline__ unsigned int pack2(float a, float b) {
    return (unsigned int)f2bf(a) | ((unsigned int)f2bf(b) << 16);
}

// ---------------------------------------------------------------- router
__global__ __launch_bounds__(256)
void router_kernel(const float* __restrict__ x, const float* __restrict__ gw,
                   const float* __restrict__ gb, unsigned short* __restrict__ xb,
                   int* __restrict__ topk_idx, float* __restrict__ topk_w,
                   int* __restrict__ counts)
{
    const int t = blockIdx.x;
    const int tid = threadIdx.x;
    __shared__ float xs[H_DIM];
    __shared__ float logits[E_NUM];
    const float* xrow = x + (size_t)t * H_DIM;

    // load row (fp32 for logits) + write bf16 copy for the GEMMs
    #pragma unroll
    for (int i = 0; i < 2; ++i) {
        int c = i * 1024 + tid * 4;
        f32x4 v = *(const f32x4*)(xrow + c);
        *(f32x4*)(xs + c) = v;
        uint2 pk; pk.x = pack2(v.x, v.y); pk.y = pack2(v.z, v.w);
        *(uint2*)(xb + (size_t)t * H_DIM + c) = pk;
    }
    __syncthreads();

    const int wave = tid >> 6, lane = tid & 63;
    for (int ee = 0; ee < 16; ++ee) {
        const int e = wave * 16 + ee;
        const float* g = gw + (size_t)e * H_DIM;
        float p = 0.f;
        #pragma unroll
        for (int i = 0; i < 8; ++i) {
            int c = (i * 64 + lane) * 4;
            f32x4 gv = *(const f32x4*)(g + c);
            f32x4 xv = *(const f32x4*)(xs + c);
            p += gv.x * xv.x + gv.y * xv.y + gv.z * xv.z + gv.w * xv.w;
        }
        #pragma unroll
        for (int s = 32; s > 0; s >>= 1) p += __shfl_xor(p, s, 64);
        if (lane == 0) logits[e] = p + gb[e];
    }
    __syncthreads();

    if (tid < 64) {   // wave 0: top-8 + softmax
        float cur = logits[tid];
        float wv[TOPK]; int wi[TOPK];
        #pragma unroll
        for (int k = 0; k < TOPK; ++k) {
            float bv = cur; int bi = tid;
            #pragma unroll
            for (int s = 32; s > 0; s >>= 1) {
                float ov = __shfl_xor(bv, s, 64);
                int   oi = __shfl_xor(bi, s, 64);
                if (ov > bv || (ov == bv && oi < bi)) { bv = ov; bi = oi; }
            }
            wv[k] = bv; wi[k] = bi;
            if (tid == bi) cur = -FLT_MAX;
        }
        if (tid == 0) {
            float mx = wv[0], sum = 0.f, ex[TOPK];
            #pragma unroll
            for (int k = 0; k < TOPK; ++k) { ex[k] = expf(wv[k] - mx); sum += ex[k]; }
            #pragma unroll
            for (int k = 0; k < TOPK; ++k) {
                topk_idx[t * TOPK + k] = wi[k];
                topk_w[t * TOPK + k]   = ex[k] / sum;
                atomicAdd(&counts[wi[k]], 1);
            }
        }
    }
}

// ---------------------------------------------------------------- scan
__global__ void scan_kernel(const int* __restrict__ counts, int* __restrict__ offsets,
                            int* __restrict__ cursors)
{
    if (threadIdx.x == 0) {
        int acc = 0;
        for (int e = 0; e < E_NUM; ++e) { offsets[e] = acc; cursors[e] = acc; acc += counts[e]; }
    }
}

// ---------------------------------------------------------------- scatter assignments
__global__ void assign_kernel(const int* __restrict__ topk_idx, const float* __restrict__ topk_w,
                              int* __restrict__ cursors, int* __restrict__ tok_of,
                              float* __restrict__ w_of)
{
    int i = blockIdx.x * 256 + threadIdx.x;
    if (i >= T_TOK * TOPK) return;
    int e = topk_idx[i];
    int pos = atomicAdd(&cursors[e], 1);
    tok_of[pos] = i >> 3;
    w_of[pos]   = topk_w[i];
}

// ---------------------------------------------------------------- GEMM1: x @ W1^T -> GeGLU -> a
__global__ __launch_bounds__(256, 2)
void gemm1_kernel(const unsigned short* __restrict__ xb, const float* __restrict__ fc1,
                  const int* __restrict__ counts, const int* __restrict__ offsets,
                  const int* __restrict__ tok_of, unsigned short* __restrict__ a_all)
{
    const int e = blockIdx.z;
    const int cnt = counts[e];
    const int m0 = blockIdx.y * BM;
    if (m0 >= cnt) return;
    const int n0 = blockIdx.x * BM;         // a-columns [n0, n0+128)
    const int off = offsets[e];
    const float* W = fc1 + (size_t)e * (size_t)(2 * I_DIM) * H_DIM;

    __shared__ unsigned short sA[BM * BK];          // 16 KB, swizzled
    __shared__ unsigned short sB[2 * BM * BK];      // 32 KB (h strip + g strip)
    __shared__ int sTok[BM];

    const int tid = threadIdx.x;
    if (tid < BM) {
        int m = m0 + tid;
        sTok[tid] = tok_of[off + (m < cnt ? m : 0)];
    }

    f32x4 accH[4][4], accG[4][4];
    #pragma unroll
    for (int m = 0; m < 4; ++m)
        #pragma unroll
        for (int n = 0; n < 4; ++n) {
            accH[m][n] = (f32x4){0.f, 0.f, 0.f, 0.f};
            accG[m][n] = (f32x4){0.f, 0.f, 0.f, 0.f};
        }

    const int wid = tid >> 6, lane = tid & 63;
    const int wm = (wid >> 1) * 64;
    const int wn = (wid & 1) * 64;
    const int fr = lane & 15;
    const int kg = lane >> 4;
    const int srow = tid >> 3, sch = tid & 7;

    __syncthreads();
    for (int k0 = 0; k0 < H_DIM; k0 += BK) {
        #pragma unroll
        for (int i = 0; i < 4; ++i) {            // stage A (gathered bf16 rows)
            int row = srow + 32 * i;
            const unsigned short* src = xb + (size_t)sTok[row] * H_DIM + k0 + sch * 8;
            i32x4 v = *(const i32x4*)src;
            int byte = (row * 128 + sch * 16) ^ ((row & 7) << 4);
            *(i32x4*)((char*)sA + byte) = v;
        }
        #pragma unroll
        for (int i = 0; i < 8; ++i) {            // stage B (fp32 W1 -> bf16), h+g strips
            int row = srow + 32 * i;             // 0..255
            int wrow = (row < BM) ? (n0 + row) : (I_DIM + n0 + (row - BM));
            const float* src = W + (size_t)wrow * H_DIM + k0 + sch * 8;
            f32x4 v0 = *(const f32x4*)src;
            f32x4 v1 = *(const f32x4*)(src + 4);
            i32x4 pk = (i32x4){(int)pack2(v0.x, v0.y), (int)pack2(v0.z, v0.w),
                               (int)pack2(v1.x, v1.y), (int)pack2(v1.z, v1.w)};
            int byte = (row * 128 + sch * 16) ^ ((row & 7) << 4);
            *(i32x4*)((char*)sB + byte) = pk;
        }
        __syncthreads();
        #pragma unroll
        for (int kk = 0; kk < 2; ++kk) {
            bf16x8 af[4], bh[4], bg[4];
            #pragma unroll
            for (int m = 0; m < 4; ++m) {
                int row = wm + m * 16 + fr;
                int byte = (row * 128 + kk * 64 + kg * 16) ^ ((row & 7) << 4);
                af[m] = *(const bf16x8*)((const char*)sA + byte);
            }
            #pragma unroll
            for (int n = 0; n < 4; ++n) {
                int rh = wn + n * 16 + fr;
                bh[n] = *(const bf16x8*)((const char*)sB + ((rh * 128 + kk * 64 + kg * 16) ^ ((rh & 7) << 4)));
                int rg = BM + wn + n * 16 + fr;
                bg[n] = *(const bf16x8*)((const char*)sB + ((rg * 128 + kk * 64 + kg * 16) ^ ((rg & 7) << 4)));
            }
            #pragma unroll
            for (int m = 0; m < 4; ++m)
                #pragma unroll
                for (int n = 0; n < 4; ++n) {
                    accH[m][n] = __builtin_amdgcn_mfma_f32_16x16x32_bf16(af[m], bh[n], accH[m][n], 0, 0, 0);
                    accG[m][n] = __builtin_amdgcn_mfma_f32_16x16x32_bf16(af[m], bg[n], accG[m][n], 0, 0, 0);
                }
        }
        __syncthreads();
    }

    // epilogue: GeGLU, store bf16 a
    #pragma unroll
    for (int m = 0; m < 4; ++m) {
        int rbase = wm + m * 16 + kg * 4;
        #pragma unroll
        for (int r = 0; r < 4; ++r) {
            int gm = m0 + rbase + r;
            if (gm < cnt) {
                size_t rowoff = (size_t)(off + gm) * I_DIM + n0 + wn;
                #pragma unroll
                for (int n = 0; n < 4; ++n) {
                    float h = accH[m][n][r];
                    float g = accG[m][n][r];
                    float a = 0.5f * h * (1.f + erff(h * 0.70710678118f)) * (g + 1.f);
                    a_all[rowoff + n * 16 + fr] = f2bf(a);
                }
            }
        }
    }
}

// ---------------------------------------------------------------- GEMM2: a @ W2^T -> scaled scatter-add
__global__ __launch_bounds__(256, 2)
void gemm2_kernel(const unsigned short* __restrict__ a_all, const float* __restrict__ fc2,
                  const int* __restrict__ counts, const int* __restrict__ offsets,
                  const int* __restrict__ tok_of, const float* __restrict__ w_of,
                  float* __restrict__ out)
{
    const int e = blockIdx.z;
    const int cnt = counts[e];
    const int m0 = blockIdx.y * BM;
    if (m0 >= cnt) return;
    const int n0 = blockIdx.x * BM;
    const int off = offsets[e];
    const float* W = fc2 + (size_t)e * (size_t)H_DIM * I_DIM;

    __shared__ unsigned short sA[BM * BK];
    __shared__ unsigned short sB[BM * BK];
    __shared__ int   sTok[BM];
    __shared__ float sWt[BM];

    const int tid = threadIdx.x;
    if (tid < BM) {
        int m = m0 + tid;
        int mm = (m < cnt) ? m : 0;
        sTok[tid] = tok_of[off + mm];
        sWt[tid]  = w_of[off + mm];
    }

    f32x4 acc[4][4];
    #pragma unroll
    for (int m = 0; m < 4; ++m)
        #pragma unroll
        for (int n = 0; n < 4; ++n) acc[m][n] = (f32x4){0.f, 0.f, 0.f, 0.f};

    const int wid = tid >> 6, lane = tid & 63;
    const int wm = (wid >> 1) * 64;
    const int wn = (wid & 1) * 64;
    const int fr = lane & 15;
    const int kg = lane >> 4;
    const int srow = tid >> 3, sch = tid & 7;

    __syncthreads();
    for (int k0 = 0; k0 < I_DIM; k0 += BK) {
        #pragma unroll
        for (int i = 0; i < 4; ++i) {            // stage A (contiguous rows, bf16)
            int row = srow + 32 * i;
            const unsigned short* src = a_all + (size_t)(off + m0 + row) * I_DIM + k0 + sch * 8;
            i32x4 v = *(const i32x4*)src;
            int byte = (row * 128 + sch * 16) ^ ((row & 7) << 4);
            *(i32x4*)((char*)sA + byte) = v;
        }
        #pragma unroll
        for (int i = 0; i < 4; ++i) {            // stage B (fp32 W2 -> bf16)
            int row = srow + 32 * i;
            const float* src = W + (size_t)(n0 + row) * I_DIM + k0 + sch * 8;
            f32x4 v0 = *(const f32x4*)src;
            f32x4 v1 = *(const f32x4*)(src + 4);
            i32x4 pk = (i32x4){(int)pack2(v0.x, v0.y), (int)pack2(v0.z, v0.w),
                               (int)pack2(v1.x, v1.y), (int)pack2(v1.z, v1.w)};
            int byte = (row * 128 + sch * 16) ^ ((row & 7) << 4);
            *(i32x4*)((char*)sB + byte) = pk;
        }
        __syncthreads();
        #pragma unroll
        for (int kk = 0; kk < 2; ++kk) {
            bf16x8 af[4], bf[4];
            #pragma unroll
            for (int m = 0; m < 4; ++m) {
                int row = wm + m * 16 + fr;
                af[m] = *(const bf16x8*)((const char*)sA + ((row * 128 + kk * 64 + kg * 16) ^ ((row & 7) << 4)));
            }
            #pragma unroll
            for (int n = 0; n < 4; ++n) {
                int row = wn + n * 16 + fr;
                bf[n] = *(const bf16x8*)((const char*)sB + ((row * 128 + kk * 64 + kg * 16) ^ ((row & 7) << 4)));
            }
            #pragma unroll
            for (int m = 0; m < 4; ++m)
                #pragma unroll
                for (int n = 0; n < 4; ++n)
                    acc[m][n] = __builtin_amdgcn_mfma_f32_16x16x32_bf16(af[m], bf[n], acc[m][n], 0, 0, 0);
        }
        __syncthreads();
    }

    // epilogue: scale by combine weight, atomic scatter-add into out
    #pragma unroll
    for (int m = 0; m < 4; ++m) {
        int rbase = wm + m * 16 + kg * 4;
        #pragma unroll
        for (int r = 0; r < 4; ++r) {
            int lm = rbase + r;
            int gm = m0 + lm;
            if (gm < cnt) {
                float c = sWt[lm];
                float* orow = out + (size_t)sTok[lm] * H_DIM + n0 + wn;
                #pragma unroll
                for (int n = 0; n < 4; ++n)
                    atomicAdd(&orow[n * 16 + fr], c * acc[m][n][r]);
            }
        }
    }
}

// ---------------------------------------------------------------- launch
extern "C" void kernel_launch(void* const* d_in, const int* in_sizes, int n_in,
                              void* d_out, int out_size, void* d_ws, size_t ws_size,
                              hipStream_t stream)
{
    const float* x   = (const float*)d_in[0];
    const float* gw  = (const float*)d_in[1];
    const float* gb  = (const float*)d_in[2];
    const float* fc1 = (const float*)d_in[3];
    const float* fc2 = (const float*)d_in[4];
    float* out = (float*)d_out;

    char* ws = (char*)d_ws;
    size_t o = 0;
    auto alloc = [&](size_t b) { void* p = ws + o; o = (o + b + 255) & ~(size_t)255; return p; };
    unsigned short* xb     = (unsigned short*)alloc((size_t)T_TOK * H_DIM * 2);
    int*            tk_idx = (int*)  alloc((size_t)T_TOK * TOPK * 4);
    float*          tk_w   = (float*)alloc((size_t)T_TOK * TOPK * 4);
    int*            counts = (int*)  alloc(E_NUM * 4);
    int*            offs   = (int*)  alloc(E_NUM * 4);
    int*            curs   = (int*)  alloc(E_NUM * 4);
    int*            tok_of = (int*)  alloc((size_t)T_TOK * TOPK * 4);
    float*          w_of   = (float*)alloc((size_t)T_TOK * TOPK * 4);
    unsigned short* a_all  = (unsigned short*)alloc((size_t)(T_TOK * TOPK + BM) * I_DIM * 2);

    hipMemsetAsync(counts, 0, E_NUM * 4, stream);
    hipMemsetAsync(out, 0, (size_t)T_TOK * H_DIM * 4, stream);

    router_kernel<<<T_TOK, 256, 0, stream>>>(x, gw, gb, xb, tk_idx, tk_w, counts);
    scan_kernel<<<1, 64, 0, stream>>>(counts, offs, curs);
    assign_kernel<<<(T_TOK * TOPK + 255) / 256, 256, 0, stream>>>(tk_idx, tk_w, curs, tok_of, w_of);
    gemm1_kernel<<<dim3(I_DIM / BM, T_TOK / BM, E_NUM), 256, 0, stream>>>(xb, fc1, counts, offs, tok_of, a_all);
    gemm2_kernel<<<dim3(H_DIM / BM, T_TOK / BM, E_NUM), 256, 0, stream>>>(a_all, fc2, counts, offs, tok_of, w_of, out);
}

// Round 2
// 1392.336 us; speedup vs baseline: 1.4942x; 1.4942x over previous
//
#include <hip/hip_runtime.h>
#include <hip/hip_bf16.h>
#include <cfloat>
#include <math.h>

#define T_TOK 4096
#define H_DIM 2048
#define E_NUM 64
#define I_DIM 1024
#define TOPK  8
#define BM    128
#define BK    64
#define MAXTILE 320   // max Sum_e ceil(cnt_e/BM) = 32768/128 + 64

typedef __attribute__((ext_vector_type(4))) float f32x4;
typedef __attribute__((ext_vector_type(8))) short bf16x8;
typedef __attribute__((ext_vector_type(4))) int   i32x4;

__device__ __forceinline__ unsigned short f2bf(float f) {
    union { float f; unsigned int u; } v; v.f = f;
    unsigned int r = v.u + 0x7FFFu + ((v.u >> 16) & 1u);  // RNE
    return (unsigned short)(r >> 16);
}
__device__ __forceinline__ unsigned int pack2(float a, float b) {
    return (unsigned int)f2bf(a) | ((unsigned int)f2bf(b) << 16);
}
__device__ __forceinline__ void gload16(const void* g, void* l) {
    __builtin_amdgcn_global_load_lds((const __attribute__((address_space(1))) unsigned int*)g,
                                     (__attribute__((address_space(3))) unsigned int*)l, 16, 0, 0);
}

// ---------------------------------------------------------------- weight convert fp32 -> bf16
__global__ __launch_bounds__(256)
void convert_kernel(const float* __restrict__ src, unsigned short* __restrict__ dst, long long n)
{
    long long i0 = ((long long)blockIdx.x * 256 + threadIdx.x) * 8;
    long long stride = (long long)gridDim.x * 256 * 8;
    for (long long i = i0; i < n; i += stride) {
        f32x4 v0 = *(const f32x4*)(src + i);
        f32x4 v1 = *(const f32x4*)(src + i + 4);
        i32x4 pk = (i32x4){(int)pack2(v0.x, v0.y), (int)pack2(v0.z, v0.w),
                           (int)pack2(v1.x, v1.y), (int)pack2(v1.z, v1.w)};
        *(i32x4*)(dst + i) = pk;
    }
}

// ---------------------------------------------------------------- router
__global__ __launch_bounds__(256)
void router_kernel(const float* __restrict__ x, const float* __restrict__ gw,
                   const float* __restrict__ gb, unsigned short* __restrict__ xb,
                   int* __restrict__ topk_idx, float* __restrict__ topk_w,
                   int* __restrict__ counts)
{
    const int t = blockIdx.x;
    const int tid = threadIdx.x;
    __shared__ float xs[H_DIM];
    __shared__ float logits[E_NUM];
    const float* xrow = x + (size_t)t * H_DIM;

    #pragma unroll
    for (int i = 0; i < 2; ++i) {
        int c = i * 1024 + tid * 4;
        f32x4 v = *(const f32x4*)(xrow + c);
        *(f32x4*)(xs + c) = v;
        uint2 pk; pk.x = pack2(v.x, v.y); pk.y = pack2(v.z, v.w);
        *(uint2*)(xb + (size_t)t * H_DIM + c) = pk;
    }
    __syncthreads();

    const int wave = tid >> 6, lane = tid & 63;
    for (int ee = 0; ee < 16; ++ee) {
        const int e = wave * 16 + ee;
        const float* g = gw + (size_t)e * H_DIM;
        float p = 0.f;
        #pragma unroll
        for (int i = 0; i < 8; ++i) {
            int c = (i * 64 + lane) * 4;
            f32x4 gv = *(const f32x4*)(g + c);
            f32x4 xv = *(const f32x4*)(xs + c);
            p += gv.x * xv.x + gv.y * xv.y + gv.z * xv.z + gv.w * xv.w;
        }
        #pragma unroll
        for (int s = 32; s > 0; s >>= 1) p += __shfl_xor(p, s, 64);
        if (lane == 0) logits[e] = p + gb[e];
    }
    __syncthreads();

    if (tid < 64) {
        float cur = logits[tid];
        float wv[TOPK]; int wi[TOPK];
        #pragma unroll
        for (int k = 0; k < TOPK; ++k) {
            float bv = cur; int bi = tid;
            #pragma unroll
            for (int s = 32; s > 0; s >>= 1) {
                float ov = __shfl_xor(bv, s, 64);
                int   oi = __shfl_xor(bi, s, 64);
                if (ov > bv || (ov == bv && oi < bi)) { bv = ov; bi = oi; }
            }
            wv[k] = bv; wi[k] = bi;
            if (tid == bi) cur = -FLT_MAX;
        }
        if (tid == 0) {
            float mx = wv[0], sum = 0.f, ex[TOPK];
            #pragma unroll
            for (int k = 0; k < TOPK; ++k) { ex[k] = expf(wv[k] - mx); sum += ex[k]; }
            #pragma unroll
            for (int k = 0; k < TOPK; ++k) {
                topk_idx[t * TOPK + k] = wi[k];
                topk_w[t * TOPK + k]   = ex[k] / sum;
                atomicAdd(&counts[wi[k]], 1);
            }
        }
    }
}

// ---------------------------------------------------------------- scan + tile list
__global__ void scan_kernel(const int* __restrict__ counts, int* __restrict__ offsets,
                            int* __restrict__ cursors, int* __restrict__ tiles,
                            int* __restrict__ ntiles)
{
    if (threadIdx.x == 0) {
        int acc = 0, nt = 0;
        for (int e = 0; e < E_NUM; ++e) {
            offsets[e] = acc; cursors[e] = acc;
            int c = counts[e];
            for (int m = 0; m * BM < c; ++m) tiles[nt++] = (e << 16) | m;
            acc += c;
        }
        *ntiles = nt;
    }
}

// ---------------------------------------------------------------- scatter assignments
__global__ void assign_kernel(const int* __restrict__ topk_idx, const float* __restrict__ topk_w,
                              int* __restrict__ cursors, int* __restrict__ tok_of,
                              float* __restrict__ w_of)
{
    int i = blockIdx.x * 256 + threadIdx.x;
    if (i >= T_TOK * TOPK) return;
    int e = topk_idx[i];
    int pos = atomicAdd(&cursors[e], 1);
    tok_of[pos] = i >> 3;
    w_of[pos]   = topk_w[i];
}

// ---------------------------------------------------------------- GEMM1 (bf16 weights, gload_lds)
__global__ __launch_bounds__(256, 2)
void gemm1_kernel(const unsigned short* __restrict__ xb, const unsigned short* __restrict__ w1b,
                  const int* __restrict__ counts, const int* __restrict__ offsets,
                  const int* __restrict__ tok_of, const int* __restrict__ tiles,
                  const int* __restrict__ ntiles, unsigned short* __restrict__ a_all)
{
    const int ty = blockIdx.y;
    if (ty >= *ntiles) return;
    const int code = tiles[ty];
    const int e = code >> 16, m0 = (code & 0xffff) * BM;
    const int cnt = counts[e], off = offsets[e];
    const int n0 = blockIdx.x * BM;
    const unsigned short* W = w1b + (size_t)e * (size_t)(2 * I_DIM) * H_DIM;

    __shared__ unsigned short sA[BM * BK];
    __shared__ unsigned short sBh[BM * BK];
    __shared__ unsigned short sBg[BM * BK];
    __shared__ int sTok[BM];

    const int tid = threadIdx.x;
    if (tid < BM) {
        int m = m0 + tid;
        sTok[tid] = tok_of[off + (m < cnt ? m : cnt - 1)];
    }
    __syncthreads();

    const int wid = tid >> 6, lane = tid & 63;
    const int srow = tid >> 3;
    const int sslot = (tid & 7) ^ (srow & 7);      // pre-swizzled source slot (rule #21)

    const unsigned short* aSrc[4];
    const unsigned short* bhSrc[4];
    const unsigned short* bgSrc[4];
    #pragma unroll
    for (int i = 0; i < 4; ++i) {
        int row = srow + 32 * i;
        aSrc[i]  = xb + (size_t)sTok[row] * H_DIM + sslot * 8;
        bhSrc[i] = W + (size_t)(n0 + row) * H_DIM + sslot * 8;
        bgSrc[i] = W + (size_t)(I_DIM + n0 + row) * H_DIM + sslot * 8;
    }

    f32x4 accH[4][4], accG[4][4];
    #pragma unroll
    for (int m = 0; m < 4; ++m)
        #pragma unroll
        for (int n = 0; n < 4; ++n) {
            accH[m][n] = (f32x4){0.f, 0.f, 0.f, 0.f};
            accG[m][n] = (f32x4){0.f, 0.f, 0.f, 0.f};
        }

    const int wm = (wid >> 1) * 64;
    const int wn = (wid & 1) * 64;
    const int fr = lane & 15;
    const int kg = lane >> 4;

    for (int k0 = 0; k0 < H_DIM; k0 += BK) {
        #pragma unroll
        for (int i = 0; i < 4; ++i) {
            int ldsrow = (32 * i + 8 * wid) * BK;
            gload16(aSrc[i]  + k0, sA  + ldsrow);
            gload16(bhSrc[i] + k0, sBh + ldsrow);
            gload16(bgSrc[i] + k0, sBg + ldsrow);
        }
        __syncthreads();
        #pragma unroll
        for (int kk = 0; kk < 2; ++kk) {
            bf16x8 af[4], bh[4], bg[4];
            #pragma unroll
            for (int m = 0; m < 4; ++m) {
                int row = wm + m * 16 + fr;
                af[m] = *(const bf16x8*)((const char*)sA + ((row * 128 + kk * 64 + kg * 16) ^ ((row & 7) << 4)));
            }
            #pragma unroll
            for (int n = 0; n < 4; ++n) {
                int row = wn + n * 16 + fr;
                int byte = (row * 128 + kk * 64 + kg * 16) ^ ((row & 7) << 4);
                bh[n] = *(const bf16x8*)((const char*)sBh + byte);
                bg[n] = *(const bf16x8*)((const char*)sBg + byte);
            }
            #pragma unroll
            for (int m = 0; m < 4; ++m)
                #pragma unroll
                for (int n = 0; n < 4; ++n) {
                    accH[m][n] = __builtin_amdgcn_mfma_f32_16x16x32_bf16(af[m], bh[n], accH[m][n], 0, 0, 0);
                    accG[m][n] = __builtin_amdgcn_mfma_f32_16x16x32_bf16(af[m], bg[n], accG[m][n], 0, 0, 0);
                }
        }
        __syncthreads();
    }

    #pragma unroll
    for (int m = 0; m < 4; ++m) {
        int rbase = wm + m * 16 + kg * 4;
        #pragma unroll
        for (int r = 0; r < 4; ++r) {
            int gm = m0 + rbase + r;
            if (gm < cnt) {
                size_t rowoff = (size_t)(off + gm) * I_DIM + n0 + wn;
                #pragma unroll
                for (int n = 0; n < 4; ++n) {
                    float h = accH[m][n][r];
                    float g = accG[m][n][r];
                    float a = 0.5f * h * (1.f + erff(h * 0.70710678118f)) * (g + 1.f);
                    a_all[rowoff + n * 16 + fr] = f2bf(a);
                }
            }
        }
    }
}

// ---------------------------------------------------------------- GEMM2 (bf16 weights, gload_lds)
__global__ __launch_bounds__(256, 2)
void gemm2_kernel(const unsigned short* __restrict__ a_all, const unsigned short* __restrict__ w2b,
                  const int* __restrict__ counts, const int* __restrict__ offsets,
                  const int* __restrict__ tok_of, const float* __restrict__ w_of,
                  const int* __restrict__ tiles, const int* __restrict__ ntiles,
                  float* __restrict__ out)
{
    const int ty = blockIdx.y;
    if (ty >= *ntiles) return;
    const int code = tiles[ty];
    const int e = code >> 16, m0 = (code & 0xffff) * BM;
    const int cnt = counts[e], off = offsets[e];
    const int n0 = blockIdx.x * BM;
    const unsigned short* W = w2b + (size_t)e * (size_t)H_DIM * I_DIM;

    __shared__ unsigned short sA[BM * BK];
    __shared__ unsigned short sB[BM * BK];
    __shared__ int   sTok[BM];
    __shared__ float sWt[BM];

    const int tid = threadIdx.x;
    if (tid < BM) {
        int m = m0 + tid;
        int mm = (m < cnt) ? m : (cnt - 1);
        sTok[tid] = tok_of[off + mm];
        sWt[tid]  = w_of[off + mm];
    }

    const int wid = tid >> 6, lane = tid & 63;
    const int srow = tid >> 3;
    const int sslot = (tid & 7) ^ (srow & 7);

    const unsigned short* aSrc[4];
    const unsigned short* bSrc[4];
    #pragma unroll
    for (int i = 0; i < 4; ++i) {
        int row = srow + 32 * i;
        aSrc[i] = a_all + (size_t)(off + m0 + row) * I_DIM + sslot * 8;
        bSrc[i] = W + (size_t)(n0 + row) * I_DIM + sslot * 8;
    }

    f32x4 acc[4][4];
    #pragma unroll
    for (int m = 0; m < 4; ++m)
        #pragma unroll
        for (int n = 0; n < 4; ++n) acc[m][n] = (f32x4){0.f, 0.f, 0.f, 0.f};

    const int wm = (wid >> 1) * 64;
    const int wn = (wid & 1) * 64;
    const int fr = lane & 15;
    const int kg = lane >> 4;

    __syncthreads();
    for (int k0 = 0; k0 < I_DIM; k0 += BK) {
        #pragma unroll
        for (int i = 0; i < 4; ++i) {
            int ldsrow = (32 * i + 8 * wid) * BK;
            gload16(aSrc[i] + k0, sA + ldsrow);
            gload16(bSrc[i] + k0, sB + ldsrow);
        }
        __syncthreads();
        #pragma unroll
        for (int kk = 0; kk < 2; ++kk) {
            bf16x8 af[4], bf[4];
            #pragma unroll
            for (int m = 0; m < 4; ++m) {
                int row = wm + m * 16 + fr;
                af[m] = *(const bf16x8*)((const char*)sA + ((row * 128 + kk * 64 + kg * 16) ^ ((row & 7) << 4)));
            }
            #pragma unroll
            for (int n = 0; n < 4; ++n) {
                int row = wn + n * 16 + fr;
                bf[n] = *(const bf16x8*)((const char*)sB + ((row * 128 + kk * 64 + kg * 16) ^ ((row & 7) << 4)));
            }
            #pragma unroll
            for (int m = 0; m < 4; ++m)
                #pragma unroll
                for (int n = 0; n < 4; ++n)
                    acc[m][n] = __builtin_amdgcn_mfma_f32_16x16x32_bf16(af[m], bf[n], acc[m][n], 0, 0, 0);
        }
        __syncthreads();
    }

    #pragma unroll
    for (int m = 0; m < 4; ++m) {
        int rbase = wm + m * 16 + kg * 4;
        #pragma unroll
        for (int r = 0; r < 4; ++r) {
            int lm = rbase + r;
            int gm = m0 + lm;
            if (gm < cnt) {
                float c = sWt[lm];
                float* orow = out + (size_t)sTok[lm] * H_DIM + n0 + wn;
                #pragma unroll
                for (int n = 0; n < 4; ++n)
                    atomicAdd(&orow[n * 16 + fr], c * acc[m][n][r]);
            }
        }
    }
}

// ---------------------------------------------------------------- legacy fallback (fp32 weights, reg-staged)
__global__ __launch_bounds__(256, 2)
void gemm1_legacy(const unsigned short* __restrict__ xb, const float* __restrict__ fc1,
                  const int* __restrict__ counts, const int* __restrict__ offsets,
                  const int* __restrict__ tok_of, unsigned short* __restrict__ a_all)
{
    const int e = blockIdx.z;
    const int cnt = counts[e];
    const int m0 = blockIdx.y * BM;
    if (m0 >= cnt) return;
    const int n0 = blockIdx.x * BM;
    const int off = offsets[e];
    const float* W = fc1 + (size_t)e * (size_t)(2 * I_DIM) * H_DIM;

    __shared__ unsigned short sA[BM * BK];
    __shared__ unsigned short sB[2 * BM * BK];
    __shared__ int sTok[BM];

    const int tid = threadIdx.x;
    if (tid < BM) {
        int m = m0 + tid;
        sTok[tid] = tok_of[off + (m < cnt ? m : 0)];
    }

    f32x4 accH[4][4], accG[4][4];
    #pragma unroll
    for (int m = 0; m < 4; ++m)
        #pragma unroll
        for (int n = 0; n < 4; ++n) {
            accH[m][n] = (f32x4){0.f, 0.f, 0.f, 0.f};
            accG[m][n] = (f32x4){0.f, 0.f, 0.f, 0.f};
        }

    const int wid = tid >> 6, lane = tid & 63;
    const int wm = (wid >> 1) * 64;
    const int wn = (wid & 1) * 64;
    const int fr = lane & 15;
    const int kg = lane >> 4;
    const int srow = tid >> 3, sch = tid & 7;

    __syncthreads();
    for (int k0 = 0; k0 < H_DIM; k0 += BK) {
        #pragma unroll
        for (int i = 0; i < 4; ++i) {
            int row = srow + 32 * i;
            const unsigned short* src = xb + (size_t)sTok[row] * H_DIM + k0 + sch * 8;
            i32x4 v = *(const i32x4*)src;
            int byte = (row * 128 + sch * 16) ^ ((row & 7) << 4);
            *(i32x4*)((char*)sA + byte) = v;
        }
        #pragma unroll
        for (int i = 0; i < 8; ++i) {
            int row = srow + 32 * i;
            int wrow = (row < BM) ? (n0 + row) : (I_DIM + n0 + (row - BM));
            const float* src = W + (size_t)wrow * H_DIM + k0 + sch * 8;
            f32x4 v0 = *(const f32x4*)src;
            f32x4 v1 = *(const f32x4*)(src + 4);
            i32x4 pk = (i32x4){(int)pack2(v0.x, v0.y), (int)pack2(v0.z, v0.w),
                               (int)pack2(v1.x, v1.y), (int)pack2(v1.z, v1.w)};
            int byte = (row * 128 + sch * 16) ^ ((row & 7) << 4);
            *(i32x4*)((char*)sB + byte) = pk;
        }
        __syncthreads();
        #pragma unroll
        for (int kk = 0; kk < 2; ++kk) {
            bf16x8 af[4], bh[4], bg[4];
            #pragma unroll
            for (int m = 0; m < 4; ++m) {
                int row = wm + m * 16 + fr;
                af[m] = *(const bf16x8*)((const char*)sA + ((row * 128 + kk * 64 + kg * 16) ^ ((row & 7) << 4)));
            }
            #pragma unroll
            for (int n = 0; n < 4; ++n) {
                int rh = wn + n * 16 + fr;
                bh[n] = *(const bf16x8*)((const char*)sB + ((rh * 128 + kk * 64 + kg * 16) ^ ((rh & 7) << 4)));
                int rg = BM + wn + n * 16 + fr;
                bg[n] = *(const bf16x8*)((const char*)sB + ((rg * 128 + kk * 64 + kg * 16) ^ ((rg & 7) << 4)));
            }
            #pragma unroll
            for (int m = 0; m < 4; ++m)
                #pragma unroll
                for (int n = 0; n < 4; ++n) {
                    accH[m][n] = __builtin_amdgcn_mfma_f32_16x16x32_bf16(af[m], bh[n], accH[m][n], 0, 0, 0);
                    accG[m][n] = __builtin_amdgcn_mfma_f32_16x16x32_bf16(af[m], bg[n], accG[m][n], 0, 0, 0);
                }
        }
        __syncthreads();
    }

    #pragma unroll
    for (int m = 0; m < 4; ++m) {
        int rbase = wm + m * 16 + kg * 4;
        #pragma unroll
        for (int r = 0; r < 4; ++r) {
            int gm = m0 + rbase + r;
            if (gm < cnt) {
                size_t rowoff = (size_t)(off + gm) * I_DIM + n0 + wn;
                #pragma unroll
                for (int n = 0; n < 4; ++n) {
                    float h = accH[m][n][r];
                    float g = accG[m][n][r];
                    float a = 0.5f * h * (1.f + erff(h * 0.70710678118f)) * (g + 1.f);
                    a_all[rowoff + n * 16 + fr] = f2bf(a);
                }
            }
        }
    }
}

__global__ __launch_bounds__(256, 2)
void gemm2_legacy(const unsigned short* __restrict__ a_all, const float* __restrict__ fc2,
                  const int* __restrict__ counts, const int* __restrict__ offsets,
                  const int* __restrict__ tok_of, const float* __restrict__ w_of,
                  float* __restrict__ out)
{
    const int e = blockIdx.z;
    const int cnt = counts[e];
    const int m0 = blockIdx.y * BM;
    if (m0 >= cnt) return;
    const int n0 = blockIdx.x * BM;
    const int off = offsets[e];
    const float* W = fc2 + (size_t)e * (size_t)H_DIM * I_DIM;

    __shared__ unsigned short sA[BM * BK];
    __shared__ unsigned short sB[BM * BK];
    __shared__ int   sTok[BM];
    __shared__ float sWt[BM];

    const int tid = threadIdx.x;
    if (tid < BM) {
        int m = m0 + tid;
        int mm = (m < cnt) ? m : 0;
        sTok[tid] = tok_of[off + mm];
        sWt[tid]  = w_of[off + mm];
    }

    f32x4 acc[4][4];
    #pragma unroll
    for (int m = 0; m < 4; ++m)
        #pragma unroll
        for (int n = 0; n < 4; ++n) acc[m][n] = (f32x4){0.f, 0.f, 0.f, 0.f};

    const int wid = tid >> 6, lane = tid & 63;
    const int wm = (wid >> 1) * 64;
    const int wn = (wid & 1) * 64;
    const int fr = lane & 15;
    const int kg = lane >> 4;
    const int srow = tid >> 3, sch = tid & 7;

    __syncthreads();
    for (int k0 = 0; k0 < I_DIM; k0 += BK) {
        #pragma unroll
        for (int i = 0; i < 4; ++i) {
            int row = srow + 32 * i;
            const unsigned short* src = a_all + (size_t)(off + m0 + row) * I_DIM + k0 + sch * 8;
            i32x4 v = *(const i32x4*)src;
            int byte = (row * 128 + sch * 16) ^ ((row & 7) << 4);
            *(i32x4*)((char*)sA + byte) = v;
        }
        #pragma unroll
        for (int i = 0; i < 4; ++i) {
            int row = srow + 32 * i;
            const float* src = W + (size_t)(n0 + row) * I_DIM + k0 + sch * 8;
            f32x4 v0 = *(const f32x4*)src;
            f32x4 v1 = *(const f32x4*)(src + 4);
            i32x4 pk = (i32x4){(int)pack2(v0.x, v0.y), (int)pack2(v0.z, v0.w),
                               (int)pack2(v1.x, v1.y), (int)pack2(v1.z, v1.w)};
            int byte = (row * 128 + sch * 16) ^ ((row & 7) << 4);
            *(i32x4*)((char*)sB + byte) = pk;
        }
        __syncthreads();
        #pragma unroll
        for (int kk = 0; kk < 2; ++kk) {
            bf16x8 af[4], bf[4];
            #pragma unroll
            for (int m = 0; m < 4; ++m) {
                int row = wm + m * 16 + fr;
                af[m] = *(const bf16x8*)((const char*)sA + ((row * 128 + kk * 64 + kg * 16) ^ ((row & 7) << 4)));
            }
            #pragma unroll
            for (int n = 0; n < 4; ++n) {
                int row = wn + n * 16 + fr;
                bf[n] = *(const bf16x8*)((const char*)sB + ((row * 128 + kk * 64 + kg * 16) ^ ((row & 7) << 4)));
            }
            #pragma unroll
            for (int m = 0; m < 4; ++m)
                #pragma unroll
                for (int n = 0; n < 4; ++n)
                    acc[m][n] = __builtin_amdgcn_mfma_f32_16x16x32_bf16(af[m], bf[n], acc[m][n], 0, 0, 0);
        }
        __syncthreads();
    }

    #pragma unroll
    for (int m = 0; m < 4; ++m) {
        int rbase = wm + m * 16 + kg * 4;
        #pragma unroll
        for (int r = 0; r < 4; ++r) {
            int lm = rbase + r;
            int gm = m0 + lm;
            if (gm < cnt) {
                float c = sWt[lm];
                float* orow = out + (size_t)sTok[lm] * H_DIM + n0 + wn;
                #pragma unroll
                for (int n = 0; n < 4; ++n)
                    atomicAdd(&orow[n * 16 + fr], c * acc[m][n][r]);
            }
        }
    }
}

// ---------------------------------------------------------------- launch
extern "C" void kernel_launch(void* const* d_in, const int* in_sizes, int n_in,
                              void* d_out, int out_size, void* d_ws, size_t ws_size,
                              hipStream_t stream)
{
    const float* x   = (const float*)d_in[0];
    const float* gw  = (const float*)d_in[1];
    const float* gb  = (const float*)d_in[2];
    const float* fc1 = (const float*)d_in[3];
    const float* fc2 = (const float*)d_in[4];
    float* out = (float*)d_out;

    char* ws = (char*)d_ws;
    size_t o = 0;
    auto alloc = [&](size_t b) { void* p = ws + o; o = (o + b + 255) & ~(size_t)255; return p; };
    unsigned short* xb     = (unsigned short*)alloc((size_t)T_TOK * H_DIM * 2);
    int*            tk_idx = (int*)  alloc((size_t)T_TOK * TOPK * 4);
    float*          tk_w   = (float*)alloc((size_t)T_TOK * TOPK * 4);
    int*            counts = (int*)  alloc(E_NUM * 4);
    int*            offs   = (int*)  alloc(E_NUM * 4);
    int*            curs   = (int*)  alloc(E_NUM * 4);
    int*            tiles  = (int*)  alloc(MAXTILE * 4);
    int*            ntiles = (int*)  alloc(4);
    int*            tok_of = (int*)  alloc((size_t)T_TOK * TOPK * 4);
    float*          w_of   = (float*)alloc((size_t)T_TOK * TOPK * 4);
    unsigned short* a_all  = (unsigned short*)alloc((size_t)(T_TOK * TOPK + BM) * I_DIM * 2);
    unsigned short* fc1b   = (unsigned short*)alloc((size_t)E_NUM * 2 * I_DIM * H_DIM * 2);
    unsigned short* fc2b   = (unsigned short*)alloc((size_t)E_NUM * H_DIM * I_DIM * 2);
    const bool fast = (o <= ws_size);

    hipMemsetAsync(counts, 0, E_NUM * 4, stream);
    hipMemsetAsync(out, 0, (size_t)T_TOK * H_DIM * 4, stream);

    router_kernel<<<T_TOK, 256, 0, stream>>>(x, gw, gb, xb, tk_idx, tk_w, counts);
    scan_kernel<<<1, 64, 0, stream>>>(counts, offs, curs, tiles, ntiles);
    assign_kernel<<<(T_TOK * TOPK + 255) / 256, 256, 0, stream>>>(tk_idx, tk_w, curs, tok_of, w_of);

    if (fast) {
        convert_kernel<<<2048, 256, 0, stream>>>(fc1, fc1b, (long long)E_NUM * 2 * I_DIM * H_DIM);
        gemm1_kernel<<<dim3(I_DIM / BM, MAXTILE), 256, 0, stream>>>(xb, fc1b, counts, offs, tok_of,
                                                                    tiles, ntiles, a_all);
        convert_kernel<<<2048, 256, 0, stream>>>(fc2, fc2b, (long long)E_NUM * H_DIM * I_DIM);
        gemm2_kernel<<<dim3(H_DIM / BM, MAXTILE), 256, 0, stream>>>(a_all, fc2b, counts, offs, tok_of,
                                                                    w_of, tiles, ntiles, out);
    } else {
        gemm1_legacy<<<dim3(I_DIM / BM, T_TOK / BM, E_NUM), 256, 0, stream>>>(xb, fc1, counts, offs, tok_of, a_all);
        gemm2_legacy<<<dim3(H_DIM / BM, T_TOK / BM, E_NUM), 256, 0, stream>>>(a_all, fc2, counts, offs, tok_of, w_of, out);
    }
}

// Round 3
// 1148.636 us; speedup vs baseline: 1.8112x; 1.2122x over previous
//
#include <hip/hip_runtime.h>
#include <hip/hip_bf16.h>
#include <cfloat>
#include <math.h>

#define T_TOK 4096
#define H_DIM 2048
#define E_NUM 64
#define I_DIM 1024
#define TOPK  8
#define BM    128
#define BK    64
#define MAXTILE 320   // max Sum_e ceil(cnt_e/BM) = 32768/128 + 64

typedef __attribute__((ext_vector_type(4))) float f32x4;
typedef __attribute__((ext_vector_type(8))) short bf16x8;
typedef __attribute__((ext_vector_type(4))) int   i32x4;

__device__ __forceinline__ unsigned short f2bf(float f) {
    union { float f; unsigned int u; } v; v.f = f;
    unsigned int r = v.u + 0x7FFFu + ((v.u >> 16) & 1u);  // RNE
    return (unsigned short)(r >> 16);
}
__device__ __forceinline__ unsigned int pack2(float a, float b) {
    return (unsigned int)f2bf(a) | ((unsigned int)f2bf(b) << 16);
}
__device__ __forceinline__ int cvtpk(float lo, float hi) {
    int r; asm("v_cvt_pk_bf16_f32 %0, %1, %2" : "=v"(r) : "v"(lo), "v"(hi)); return r;
}
__device__ __forceinline__ void gload16(const void* g, void* l) {
    __builtin_amdgcn_global_load_lds((const __attribute__((address_space(1))) unsigned int*)g,
                                     (__attribute__((address_space(3))) unsigned int*)l, 16, 0, 0);
}

// ---------------------------------------------------------------- router
__global__ __launch_bounds__(256)
void router_kernel(const float* __restrict__ x, const float* __restrict__ gw,
                   const float* __restrict__ gb, unsigned short* __restrict__ xb,
                   int* __restrict__ topk_idx, float* __restrict__ topk_w,
                   int* __restrict__ counts)
{
    const int t = blockIdx.x;
    const int tid = threadIdx.x;
    __shared__ float xs[H_DIM];
    __shared__ float logits[E_NUM];
    const float* xrow = x + (size_t)t * H_DIM;

    #pragma unroll
    for (int i = 0; i < 2; ++i) {
        int c = i * 1024 + tid * 4;
        f32x4 v = *(const f32x4*)(xrow + c);
        *(f32x4*)(xs + c) = v;
        uint2 pk; pk.x = pack2(v.x, v.y); pk.y = pack2(v.z, v.w);
        *(uint2*)(xb + (size_t)t * H_DIM + c) = pk;
    }
    __syncthreads();

    const int wave = tid >> 6, lane = tid & 63;
    for (int ee = 0; ee < 16; ++ee) {
        const int e = wave * 16 + ee;
        const float* g = gw + (size_t)e * H_DIM;
        float p = 0.f;
        #pragma unroll
        for (int i = 0; i < 8; ++i) {
            int c = (i * 64 + lane) * 4;
            f32x4 gv = *(const f32x4*)(g + c);
            f32x4 xv = *(const f32x4*)(xs + c);
            p += gv.x * xv.x + gv.y * xv.y + gv.z * xv.z + gv.w * xv.w;
        }
        #pragma unroll
        for (int s = 32; s > 0; s >>= 1) p += __shfl_xor(p, s, 64);
        if (lane == 0) logits[e] = p + gb[e];
    }
    __syncthreads();

    if (tid < 64) {
        float cur = logits[tid];
        float wv[TOPK]; int wi[TOPK];
        #pragma unroll
        for (int k = 0; k < TOPK; ++k) {
            float bv = cur; int bi = tid;
            #pragma unroll
            for (int s = 32; s > 0; s >>= 1) {
                float ov = __shfl_xor(bv, s, 64);
                int   oi = __shfl_xor(bi, s, 64);
                if (ov > bv || (ov == bv && oi < bi)) { bv = ov; bi = oi; }
            }
            wv[k] = bv; wi[k] = bi;
            if (tid == bi) cur = -FLT_MAX;
        }
        if (tid == 0) {
            float mx = wv[0], sum = 0.f, ex[TOPK];
            #pragma unroll
            for (int k = 0; k < TOPK; ++k) { ex[k] = expf(wv[k] - mx); sum += ex[k]; }
            #pragma unroll
            for (int k = 0; k < TOPK; ++k) {
                topk_idx[t * TOPK + k] = wi[k];
                topk_w[t * TOPK + k]   = ex[k] / sum;
                atomicAdd(&counts[wi[k]], 1);
            }
        }
    }
}

// ---------------------------------------------------------------- scan + tile list
__global__ void scan_kernel(const int* __restrict__ counts, int* __restrict__ offsets,
                            int* __restrict__ cursors, int* __restrict__ tiles,
                            int* __restrict__ ntiles)
{
    if (threadIdx.x == 0) {
        int acc = 0, nt = 0;
        for (int e = 0; e < E_NUM; ++e) {
            offsets[e] = acc; cursors[e] = acc;
            int c = counts[e];
            for (int m = 0; m * BM < c; ++m) tiles[nt++] = (e << 16) | m;
            acc += c;
        }
        *ntiles = nt;
    }
}

// ---------------------------------------------------------------- scatter assignments
__global__ void assign_kernel(const int* __restrict__ topk_idx, const float* __restrict__ topk_w,
                              int* __restrict__ cursors, int* __restrict__ tok_of,
                              float* __restrict__ w_of)
{
    int i = blockIdx.x * 256 + threadIdx.x;
    if (i >= T_TOK * TOPK) return;
    int e = topk_idx[i];
    int pos = atomicAdd(&cursors[e], 1);
    tok_of[pos] = i >> 3;
    w_of[pos]   = topk_w[i];
}

// ---------------------------------------------------------------- GEMM1: fused fp32->bf16 weight staging
// A (xb, bf16) via global_load_lds double-buffered; B (fc1 fp32, h+g strips) reg-staged
// with issue-early/convert-late (T14); 2-barrier pipelined K-loop.
__global__ __launch_bounds__(256, 2)
void gemm1_kernel(const unsigned short* __restrict__ xb, const float* __restrict__ fc1,
                  const int* __restrict__ counts, const int* __restrict__ offsets,
                  const int* __restrict__ tok_of, const int* __restrict__ tiles,
                  const int* __restrict__ ntiles, unsigned short* __restrict__ a_all)
{
    const int ty = blockIdx.y;
    if (ty >= *ntiles) return;
    const int code = tiles[ty];
    const int e = code >> 16, m0 = (code & 0xffff) * BM;
    const int cnt = counts[e], off = offsets[e];
    const int n0 = blockIdx.x * BM;
    const float* W = fc1 + (size_t)e * (size_t)(2 * I_DIM) * H_DIM;

    __shared__ unsigned short sA[2][BM * BK];   // 2 x 16 KB, A double-buffer
    __shared__ unsigned short sB[2 * BM * BK];  // 32 KB, h+g strips, single buffer
    __shared__ int sTok[BM];

    const int tid = threadIdx.x;
    if (tid < BM) {
        int m = m0 + tid;
        sTok[tid] = tok_of[off + (m < cnt ? m : cnt - 1)];
    }
    __syncthreads();

    const int wid = tid >> 6, lane = tid & 63;
    const int srow = tid >> 3, sch = tid & 7;
    const int sslot = sch ^ (srow & 7);          // pre-swizzled source slot for A (rule #21)

    const unsigned short* aSrc[4];
    const float* bSrc[8];
    #pragma unroll
    for (int i = 0; i < 4; ++i) {
        int row = srow + 32 * i;
        aSrc[i] = xb + (size_t)sTok[row] * H_DIM + sslot * 8;
    }
    #pragma unroll
    for (int i = 0; i < 8; ++i) {
        int row = srow + 32 * i;                 // 0..255 across both strips
        int wrow = (row < BM) ? (n0 + row) : (I_DIM + n0 + (row - BM));
        bSrc[i] = W + (size_t)wrow * H_DIM + sch * 8;
    }

    f32x4 accH[4][4], accG[4][4];
    #pragma unroll
    for (int m = 0; m < 4; ++m)
        #pragma unroll
        for (int n = 0; n < 4; ++n) {
            accH[m][n] = (f32x4){0.f, 0.f, 0.f, 0.f};
            accG[m][n] = (f32x4){0.f, 0.f, 0.f, 0.f};
        }

    const int wm = (wid >> 1) * 64;
    const int wn = (wid & 1) * 64;
    const int fr = lane & 15;
    const int kg = lane >> 4;

    f32x4 br[16];                                // in-flight B regs (64 VGPR)

    auto issueB = [&](int k0) {
        #pragma unroll
        for (int i = 0; i < 8; ++i) {
            br[2 * i]     = *(const f32x4*)(bSrc[i] + k0);
            br[2 * i + 1] = *(const f32x4*)(bSrc[i] + k0 + 4);
        }
    };
    auto issueA = [&](int k0, int buf) {
        #pragma unroll
        for (int i = 0; i < 4; ++i)
            gload16(aSrc[i] + k0, &sA[buf][(32 * i + 8 * wid) * BK]);
    };
    auto writeB = [&]() {
        #pragma unroll
        for (int i = 0; i < 8; ++i) {
            int row = srow + 32 * i;
            i32x4 pk = (i32x4){cvtpk(br[2*i].x,   br[2*i].y),
                               cvtpk(br[2*i].z,   br[2*i].w),
                               cvtpk(br[2*i+1].x, br[2*i+1].y),
                               cvtpk(br[2*i+1].z, br[2*i+1].w)};
            int byte = (row * 128 + sch * 16) ^ ((row & 7) << 4);
            *(i32x4*)((char*)sB + byte) = pk;
        }
    };
    auto compute = [&](int buf) {
        #pragma unroll
        for (int kk = 0; kk < 2; ++kk) {
            bf16x8 af[4], bh[4], bg[4];
            #pragma unroll
            for (int m = 0; m < 4; ++m) {
                int row = wm + m * 16 + fr;
                af[m] = *(const bf16x8*)((const char*)sA[buf] +
                        ((row * 128 + kk * 64 + kg * 16) ^ ((row & 7) << 4)));
            }
            #pragma unroll
            for (int n = 0; n < 4; ++n) {
                int rh = wn + n * 16 + fr;
                bh[n] = *(const bf16x8*)((const char*)sB +
                        ((rh * 128 + kk * 64 + kg * 16) ^ ((rh & 7) << 4)));
                int rg = BM + rh;
                bg[n] = *(const bf16x8*)((const char*)sB +
                        ((rg * 128 + kk * 64 + kg * 16) ^ ((rg & 7) << 4)));
            }
            #pragma unroll
            for (int m = 0; m < 4; ++m)
                #pragma unroll
                for (int n = 0; n < 4; ++n) {
                    accH[m][n] = __builtin_amdgcn_mfma_f32_16x16x32_bf16(af[m], bh[n], accH[m][n], 0, 0, 0);
                    accG[m][n] = __builtin_amdgcn_mfma_f32_16x16x32_bf16(af[m], bg[n], accG[m][n], 0, 0, 0);
                }
        }
    };

    const int NT = H_DIM / BK;                   // 32
    issueB(0);
    issueA(0, 0);
    __syncthreads();                             // drains vmcnt: br + sA[0] ready
    writeB();
    __syncthreads();
    int cur = 0;
    for (int t = 0; t < NT; ++t) {
        const bool more = (t + 1) < NT;
        if (more) { issueB((t + 1) * BK); issueA((t + 1) * BK, cur ^ 1); }
        compute(cur);                            // loads fly under MFMA
        __syncthreads();                         // drain: br landed, sB reads done
        if (more) writeB();
        __syncthreads();
        cur ^= 1;
    }

    #pragma unroll
    for (int m = 0; m < 4; ++m) {
        int rbase = wm + m * 16 + kg * 4;
        #pragma unroll
        for (int r = 0; r < 4; ++r) {
            int gm = m0 + rbase + r;
            if (gm < cnt) {
                size_t rowoff = (size_t)(off + gm) * I_DIM + n0 + wn;
                #pragma unroll
                for (int n = 0; n < 4; ++n) {
                    float h = accH[m][n][r];
                    float g = accG[m][n][r];
                    float a = 0.5f * h * (1.f + erff(h * 0.70710678118f)) * (g + 1.f);
                    a_all[rowoff + n * 16 + fr] = f2bf(a);
                }
            }
        }
    }
}

// ---------------------------------------------------------------- GEMM2: fused fp32->bf16 weight staging
__global__ __launch_bounds__(256, 2)
void gemm2_kernel(const unsigned short* __restrict__ a_all, const float* __restrict__ fc2,
                  const int* __restrict__ counts, const int* __restrict__ offsets,
                  const int* __restrict__ tok_of, const float* __restrict__ w_of,
                  const int* __restrict__ tiles, const int* __restrict__ ntiles,
                  float* __restrict__ out)
{
    const int ty = blockIdx.y;
    if (ty >= *ntiles) return;
    const int code = tiles[ty];
    const int e = code >> 16, m0 = (code & 0xffff) * BM;
    const int cnt = counts[e], off = offsets[e];
    const int n0 = blockIdx.x * BM;
    const float* W = fc2 + (size_t)e * (size_t)H_DIM * I_DIM;

    __shared__ unsigned short sA[2][BM * BK];    // 2 x 16 KB
    __shared__ unsigned short sB[BM * BK];       // 16 KB
    __shared__ int   sTok[BM];
    __shared__ float sWt[BM];

    const int tid = threadIdx.x;
    if (tid < BM) {
        int m = m0 + tid;
        int mm = (m < cnt) ? m : (cnt - 1);
        sTok[tid] = tok_of[off + mm];
        sWt[tid]  = w_of[off + mm];
    }

    const int wid = tid >> 6, lane = tid & 63;
    const int srow = tid >> 3, sch = tid & 7;
    const int sslot = sch ^ (srow & 7);

    const unsigned short* aSrc[4];
    const float* bSrc[4];
    #pragma unroll
    for (int i = 0; i < 4; ++i) {
        int row = srow + 32 * i;
        aSrc[i] = a_all + (size_t)(off + m0 + row) * I_DIM + sslot * 8;
        bSrc[i] = W + (size_t)(n0 + row) * I_DIM + sch * 8;
    }

    f32x4 acc[4][4];
    #pragma unroll
    for (int m = 0; m < 4; ++m)
        #pragma unroll
        for (int n = 0; n < 4; ++n) acc[m][n] = (f32x4){0.f, 0.f, 0.f, 0.f};

    const int wm = (wid >> 1) * 64;
    const int wn = (wid & 1) * 64;
    const int fr = lane & 15;
    const int kg = lane >> 4;

    f32x4 br[8];

    auto issueB = [&](int k0) {
        #pragma unroll
        for (int i = 0; i < 4; ++i) {
            br[2 * i]     = *(const f32x4*)(bSrc[i] + k0);
            br[2 * i + 1] = *(const f32x4*)(bSrc[i] + k0 + 4);
        }
    };
    auto issueA = [&](int k0, int buf) {
        #pragma unroll
        for (int i = 0; i < 4; ++i)
            gload16(aSrc[i] + k0, &sA[buf][(32 * i + 8 * wid) * BK]);
    };
    auto writeB = [&]() {
        #pragma unroll
        for (int i = 0; i < 4; ++i) {
            int row = srow + 32 * i;
            i32x4 pk = (i32x4){cvtpk(br[2*i].x,   br[2*i].y),
                               cvtpk(br[2*i].z,   br[2*i].w),
                               cvtpk(br[2*i+1].x, br[2*i+1].y),
                               cvtpk(br[2*i+1].z, br[2*i+1].w)};
            int byte = (row * 128 + sch * 16) ^ ((row & 7) << 4);
            *(i32x4*)((char*)sB + byte) = pk;
        }
    };
    auto compute = [&](int buf) {
        #pragma unroll
        for (int kk = 0; kk < 2; ++kk) {
            bf16x8 af[4], bfr[4];
            #pragma unroll
            for (int m = 0; m < 4; ++m) {
                int row = wm + m * 16 + fr;
                af[m] = *(const bf16x8*)((const char*)sA[buf] +
                        ((row * 128 + kk * 64 + kg * 16) ^ ((row & 7) << 4)));
            }
            #pragma unroll
            for (int n = 0; n < 4; ++n) {
                int row = wn + n * 16 + fr;
                bfr[n] = *(const bf16x8*)((const char*)sB +
                        ((row * 128 + kk * 64 + kg * 16) ^ ((row & 7) << 4)));
            }
            #pragma unroll
            for (int m = 0; m < 4; ++m)
                #pragma unroll
                for (int n = 0; n < 4; ++n)
                    acc[m][n] = __builtin_amdgcn_mfma_f32_16x16x32_bf16(af[m], bfr[n], acc[m][n], 0, 0, 0);
        }
    };

    const int NT = I_DIM / BK;                   // 16
    issueB(0);
    issueA(0, 0);
    __syncthreads();
    writeB();
    __syncthreads();
    int cur = 0;
    for (int t = 0; t < NT; ++t) {
        const bool more = (t + 1) < NT;
        if (more) { issueB((t + 1) * BK); issueA((t + 1) * BK, cur ^ 1); }
        compute(cur);
        __syncthreads();
        if (more) writeB();
        __syncthreads();
        cur ^= 1;
    }

    #pragma unroll
    for (int m = 0; m < 4; ++m) {
        int rbase = wm + m * 16 + kg * 4;
        #pragma unroll
        for (int r = 0; r < 4; ++r) {
            int lm = rbase + r;
            int gm = m0 + lm;
            if (gm < cnt) {
                float c = sWt[lm];
                float* orow = out + (size_t)sTok[lm] * H_DIM + n0 + wn;
                #pragma unroll
                for (int n = 0; n < 4; ++n)
                    atomicAdd(&orow[n * 16 + fr], c * acc[m][n][r]);
            }
        }
    }
}

// ---------------------------------------------------------------- launch
extern "C" void kernel_launch(void* const* d_in, const int* in_sizes, int n_in,
                              void* d_out, int out_size, void* d_ws, size_t ws_size,
                              hipStream_t stream)
{
    const float* x   = (const float*)d_in[0];
    const float* gw  = (const float*)d_in[1];
    const float* gb  = (const float*)d_in[2];
    const float* fc1 = (const float*)d_in[3];
    const float* fc2 = (const float*)d_in[4];
    float* out = (float*)d_out;

    char* ws = (char*)d_ws;
    size_t o = 0;
    auto alloc = [&](size_t b) { void* p = ws + o; o = (o + b + 255) & ~(size_t)255; return p; };
    unsigned short* xb     = (unsigned short*)alloc((size_t)T_TOK * H_DIM * 2);
    int*            tk_idx = (int*)  alloc((size_t)T_TOK * TOPK * 4);
    float*          tk_w   = (float*)alloc((size_t)T_TOK * TOPK * 4);
    int*            counts = (int*)  alloc(E_NUM * 4);
    int*            offs   = (int*)  alloc(E_NUM * 4);
    int*            curs   = (int*)  alloc(E_NUM * 4);
    int*            tiles  = (int*)  alloc(MAXTILE * 4);
    int*            ntiles = (int*)  alloc(4);
    int*            tok_of = (int*)  alloc((size_t)T_TOK * TOPK * 4);
    float*          w_of   = (float*)alloc((size_t)T_TOK * TOPK * 4);
    unsigned short* a_all  = (unsigned short*)alloc((size_t)(T_TOK * TOPK + BM) * I_DIM * 2);
    (void)ws_size;

    hipMemsetAsync(counts, 0, E_NUM * 4, stream);
    hipMemsetAsync(out, 0, (size_t)T_TOK * H_DIM * 4, stream);

    router_kernel<<<T_TOK, 256, 0, stream>>>(x, gw, gb, xb, tk_idx, tk_w, counts);
    scan_kernel<<<1, 64, 0, stream>>>(counts, offs, curs, tiles, ntiles);
    assign_kernel<<<(T_TOK * TOPK + 255) / 256, 256, 0, stream>>>(tk_idx, tk_w, curs, tok_of, w_of);
    gemm1_kernel<<<dim3(I_DIM / BM, MAXTILE), 256, 0, stream>>>(xb, fc1, counts, offs, tok_of,
                                                                tiles, ntiles, a_all);
    gemm2_kernel<<<dim3(H_DIM / BM, MAXTILE), 256, 0, stream>>>(a_all, fc2, counts, offs, tok_of,
                                                                w_of, tiles, ntiles, out);
}